// Round 6
// baseline (2608.527 us; speedup 1.0000x reference)
//
#include <hip/hip_runtime.h>

// Problem constants
#define V_  32000
#define E_  256
#define H_  256
#define S_  128
#define B_  64
#define HID_ 30

typedef float f32x2 __attribute__((ext_vector_type(2)));

// Accurate f32 activations
__device__ __forceinline__ float sigmoid_acc(float x) {
    return 1.0f / (1.0f + expf(-x));
}
__device__ __forceinline__ float tanh_acc(float x) {
    return tanhf(x);
}

// ---------------------------------------------------------------------------
// K0: build sTp — streamed partner-half weight pairs, transposed for
// coalesced per-step reload. sTp[v][j][t]: v = dir*2+side, j = 0..11,
// t = thread id 0..511 of WG(dir,side); row(t) = (t>>7)*256+side*128+(t&127),
// col = (side^1)*128 + 104 + 2j.
// ---------------------------------------------------------------------------
#define PS_ 12

__global__ __launch_bounds__(256) void prep_sT_kernel(
    const float* __restrict__ Whh_f, const float* __restrict__ Whh_b,
    f32x2* __restrict__ sTp) {
    int i = blockIdx.x * 256 + threadIdx.x;   // < 4*12*512
    if (i >= 4 * PS_ * 512) return;
    int t = i & 511;
    int j = (i >> 9) % PS_;
    int v = i / (PS_ * 512);                  // 0..3
    int dir = v >> 1, side = v & 1;
    int row = ((t >> 7) << 8) + (side << 7) + (t & 127);
    int col = ((side ^ 1) << 7) + 104 + 2 * j;
    const float* Whh = dir ? Whh_b : Whh_f;
    const float* src = Whh + (size_t)row * H_ + col;
    sTp[i] = (f32x2){src[0], src[1]};
}

// ---------------------------------------------------------------------------
// K1: f32 input-projection GEMM with fused embedding gather.
// 128x128 tile, 8x8 per thread, KC=32 via LDS. grid (512, 2), block 256.
// ---------------------------------------------------------------------------
#define GKC 32
#define GLD 132

__global__ __launch_bounds__(256, 4) void gemm2_kernel(
    const int* __restrict__ concepts, const float* __restrict__ embedding,
    const float* __restrict__ Wih_f, const float* __restrict__ Wih_b,
    float* __restrict__ Xg) {
    __shared__ float As[GKC][GLD];
    __shared__ float Bs[GKC][GLD];
    const int dir = blockIdx.y;
    const float* Wih = dir ? Wih_b : Wih_f;
    const int mt = blockIdx.x >> 3;
    const int nt = blockIdx.x & 7;
    const int m0 = mt * 128, n0 = nt * 128;
    const int t = threadIdx.x;
    const int tm = (t & 15) * 4;
    const int tn = (t >> 4) * 4;

    int cid[4], rr[4];
#pragma unroll
    for (int i = 0; i < 4; ++i) {
        int flat = t + 256 * i;
        rr[i] = flat >> 3;
        cid[i] = concepts[m0 + rr[i]];
    }

    float acc[8][8];
#pragma unroll
    for (int i = 0; i < 8; ++i)
#pragma unroll
        for (int j = 0; j < 8; ++j) acc[i][j] = 0.f;

    for (int kk = 0; kk < E_; kk += GKC) {
        __syncthreads();
#pragma unroll
        for (int i = 0; i < 4; ++i) {
            int flat = t + 256 * i;
            int r = rr[i];
            int kq = (flat & 7) * 4;
            float4 av = *(const float4*)&embedding[(size_t)cid[i] * E_ + kk + kq];
            float4 bv = *(const float4*)&Wih[(size_t)(n0 + r) * E_ + kk + kq];
            As[kq + 0][r] = av.x; As[kq + 1][r] = av.y;
            As[kq + 2][r] = av.z; As[kq + 3][r] = av.w;
            Bs[kq + 0][r] = bv.x; Bs[kq + 1][r] = bv.y;
            Bs[kq + 2][r] = bv.z; Bs[kq + 3][r] = bv.w;
        }
        __syncthreads();
#pragma unroll
        for (int k = 0; k < GKC; ++k) {
            float4 a0 = *(const float4*)&As[k][tm];
            float4 a1 = *(const float4*)&As[k][tm + 64];
            float4 b0 = *(const float4*)&Bs[k][tn];
            float4 b1 = *(const float4*)&Bs[k][tn + 64];
            float am[8] = {a0.x, a0.y, a0.z, a0.w, a1.x, a1.y, a1.z, a1.w};
            float bn[8] = {b0.x, b0.y, b0.z, b0.w, b1.x, b1.y, b1.z, b1.w};
#pragma unroll
            for (int i = 0; i < 8; ++i)
#pragma unroll
                for (int j = 0; j < 8; ++j)
                    acc[i][j] = fmaf(am[i], bn[j], acc[i][j]);
        }
    }
    float* out = Xg + ((size_t)dir * 8192 + m0) * 1024 + n0;
#pragma unroll
    for (int i = 0; i < 8; ++i) {
        int mr = (i < 4) ? (tm + i) : (tm + 60 + i);
        *(float4*)&out[(size_t)mr * 1024 + tn] =
            make_float4(acc[i][0], acc[i][1], acc[i][2], acc[i][3]);
        *(float4*)&out[(size_t)mr * 1024 + tn + 64] =
            make_float4(acc[i][4], acc[i][5], acc[i][6], acc[i][7]);
    }
}

// ---------------------------------------------------------------------------
// K2: LSTM, unit-split halves with h-exchange, register budget = round 4's
// proven fit (160 f32 pinned weights/thread).
// Grid 256 coop, block 512. side = blockIdx>>7 (pair = blockIdx, blockIdx+128
// -> same XCD under i%8 round-robin), P = blockIdx&127, dir = P&1, b = P>>1.
// Thread t: gate gt=t>>7, unit ul=t&127, row = gt*256+side*128+ul.
// Own half (cols of own units, h local): 46 reg + 18 LDS pairs.
// Partner half: 34 reg + 18 LDS + 12 streamed (volatile, coalesced) pairs.
// Partner h arrives as packed (tag<<32|f32) relaxed agent atomics; the first
// poll load is issued BEFORE the own dot so the LLC round trip hides.
// ---------------------------------------------------------------------------
#define OR_ 46
#define OL_ 18
#define PR_ 34
#define PL_ 18
#define NL_ (OL_ + PL_)   // 36 pair-cols in LDS = 147456 B

__global__ __launch_bounds__(512, 2) void lstm_x_kernel(
    const float* __restrict__ Xg,     // [2][8192][1024]
    const float* __restrict__ Whh_f, const float* __restrict__ Whh_b,
    const float* __restrict__ b_f, const float* __restrict__ b_b,
    const int* __restrict__ lens,
    float* __restrict__ enc,          // [B][S][512]
    unsigned long long* __restrict__ Xch,   // [P=128][2 par][2 side][128]
    const f32x2* __restrict__ sTp) {  // [4][12][512]
    extern __shared__ f32x2 Wl[];     // [NL_][512]
    __shared__ f32x2 h_sh2[128];      // full h as 128 pairs
    __shared__ float g_sh[4][128];
    const int w = blockIdx.x;
    const int side = w >> 7;          // pair partner: w ^ 128
    const int P = w & 127;
    const int dir = P & 1, b = P >> 1;
    const int t = threadIdx.x;
    const int gt = t >> 7, ul = t & 127;
    const int row = (gt << 8) + (side << 7) + ul;
    const int obase = side << 7, pbase = obase ^ 128;
    const float* Whh = dir ? Whh_b : Whh_f;
    const int len = lens[b];

    // pin weights
    f32x2 wO[OR_], wP[PR_];
    {
        const f32x2* wr = (const f32x2*)(Whh + (size_t)row * H_);
        const f32x2* ow = wr + (obase >> 1);
        const f32x2* pw = wr + (pbase >> 1);
#pragma unroll
        for (int j = 0; j < OR_; ++j) wO[j] = ow[j];
#pragma unroll
        for (int j = 0; j < PR_; ++j) wP[j] = pw[j];
#pragma unroll
        for (int j = 0; j < OL_; ++j) Wl[j * 512 + t] = ow[OR_ + j];
#pragma unroll
        for (int j = 0; j < PL_; ++j) Wl[(OL_ + j) * 512 + t] = pw[PR_ + j];
    }
    const float bias = (dir ? b_b : b_f)[row];
    // volatile: force per-step reload (keeps them OUT of the register budget)
    volatile const f32x2* sT0 = sTp + (size_t)(dir * 2 + side) * PS_ * 512;

    if (t < 128) h_sh2[t] = (f32x2){0.f, 0.f};
    float c = 0.f;                    // cell state (t<128)
    __syncthreads();

    int srow = dir ? (len - 1) : 0;   // len >= 1 guaranteed
    float xv = Xg[((size_t)dir * 8192 + (size_t)srow * B_ + b) * 1024 + row];

    for (int s = 0; s < S_; ++s) {
        // streamed partner pairs (cols pbase+104..127), coalesced, in flight
        f32x2 ws[PS_];
#pragma unroll
        for (int j = 0; j < PS_; ++j) ws[j] = sT0[j * 512 + t];

        // speculative first poll (flight overlaps own dot)
        unsigned long long* ps =
            Xch + (((size_t)P * 2 + (s & 1)) * 2 + (side ^ 1)) * 128 + (t & 127);
        unsigned long long v0 = 0;
        if (t < 128)
            v0 = __hip_atomic_load(ps, __ATOMIC_RELAXED, __HIP_MEMORY_SCOPE_AGENT);

        // next-step x prefetch
        int srow_n = 0;
        float xv_n = 0.f;
        if (s + 1 < S_) {
            int ns = s + 1;
            srow_n = dir ? ((ns < len) ? (len - 1 - ns) : ns) : ns;
            xv_n = Xg[((size_t)dir * 8192 + (size_t)srow_n * B_ + b) * 1024 + row];
        }

        // A: own-half dot (h local from previous finalize)
        f32x2 a = (f32x2){0.f, 0.f};
        const f32x2* ho = h_sh2 + (obase >> 1);
#pragma unroll
        for (int j = 0; j < OR_; ++j)
            a = __builtin_elementwise_fma(wO[j], ho[j], a);
#pragma unroll
        for (int j = 0; j < OL_; ++j)
            a = __builtin_elementwise_fma(Wl[j * 512 + t], ho[OR_ + j], a);

        // B: complete the poll for partner h(s)
        if (t < 128) {
            while ((unsigned)(v0 >> 32) != (unsigned)s)
                v0 = __hip_atomic_load(ps, __ATOMIC_RELAXED,
                                       __HIP_MEMORY_SCOPE_AGENT);
            ((float*)h_sh2)[pbase + t] = __uint_as_float((unsigned)v0);
        }
        __syncthreads();   // #1: partner h in LDS

        // C: partner-half dot
        const f32x2* hp = h_sh2 + (pbase >> 1);
#pragma unroll
        for (int j = 0; j < PR_; ++j)
            a = __builtin_elementwise_fma(wP[j], hp[j], a);
#pragma unroll
        for (int j = 0; j < PL_; ++j)
            a = __builtin_elementwise_fma(Wl[(OL_ + j) * 512 + t],
                                          hp[PR_ + j], a);
#pragma unroll
        for (int j = 0; j < PS_; ++j)
            a = __builtin_elementwise_fma(ws[j], hp[PR_ + PL_ + j], a);
        float gate = a.x + a.y + bias + xv;
        g_sh[gt][ul] = (gt == 2) ? tanh_acc(gate) : sigmoid_acc(gate);
        __syncthreads();   // #2: all gates ready; h(s) fully consumed

        // D: finalize own units, write enc, publish h(s+1)
        if (t < 128) {
            float iv = g_sh[0][ul], fv = g_sh[1][ul];
            float gg = g_sh[2][ul], ov = g_sh[3][ul];
            c = fv * c + iv * gg;
            float h = ov * tanh_acc(c);
            ((float*)h_sh2)[obase + ul] = h;
            int orow = dir ? srow : s;
            enc[((size_t)b * S_ + orow) * 512 + dir * H_ + obase + ul] =
                (orow < len) ? h : 0.f;
            if (s + 1 < S_) {
                unsigned long long pk =
                    ((unsigned long long)(unsigned)(s + 1) << 32) |
                    (unsigned long long)__float_as_uint(h);
                __hip_atomic_store(
                    Xch + (((size_t)P * 2 + ((s + 1) & 1)) * 2 + side) * 128 + ul,
                    pk, __ATOMIC_RELAXED, __HIP_MEMORY_SCOPE_AGENT);
            }
        }
        __syncthreads();   // #3: own h ready for next step's own dot

        srow = srow_n;
        xv = xv_n;
    }
}

// ---------------------------------------------------------------------------
// K3: U = enc@Ua^T, W = enc@Wa^T
// ---------------------------------------------------------------------------
__global__ __launch_bounds__(256) void uw_kernel(
    const float* __restrict__ enc, const float* __restrict__ Ua,
    const float* __restrict__ Wa, float* __restrict__ U, float* __restrict__ Wout) {
    __shared__ float wgt[60][129];
    __shared__ float erow[4][128];
    const int tid = threadIdx.x;
    const int b = blockIdx.y, s0 = blockIdx.x * 32;
    const int rl = tid >> 6;
    const int d = tid & 63;
    const int dd = d & 31;
    const int isW = d >> 5;
    float acc[8];
#pragma unroll
    for (int i = 0; i < 8; ++i) acc[i] = 0.f;

    for (int kk = 0; kk < 4; ++kk) {
        __syncthreads();
        for (int i = tid; i < 30 * 128; i += 256) {
            int r = i >> 7, k = i & 127;
            wgt[r][k] = Ua[(size_t)r * 512 + kk * 128 + k];
            wgt[r + 30][k] = Wa[(size_t)r * 512 + kk * 128 + k];
        }
        for (int chunk = 0; chunk < 8; ++chunk) {
            __syncthreads();
            for (int i = tid; i < 4 * 128; i += 256) {
                int r = i >> 7, k = i & 127;
                erow[r][k] = enc[((size_t)b * S_ + (s0 + chunk * 4 + r)) * 512 + kk * 128 + k];
            }
            __syncthreads();
            if (dd < HID_) {
                const float* wr = wgt[dd + 30 * isW];
                const float* er = erow[rl];
                float a = acc[chunk];
#pragma unroll
                for (int k = 0; k < 128; ++k) a = fmaf(er[k], wr[k], a);
                acc[chunk] = a;
            }
        }
    }
    if (dd < HID_) {
        float* dst = isW ? Wout : U;
#pragma unroll
        for (int chunk = 0; chunk < 8; ++chunk)
            dst[((size_t)b * S_ + (s0 + chunk * 4 + rl)) * 32 + dd] = acc[chunk];
    }
}

// ---------------------------------------------------------------------------
// K4: scores + predictions
// ---------------------------------------------------------------------------
__global__ __launch_bounds__(256) void scores_kernel(
    const float* __restrict__ U, const float* __restrict__ W,
    const float* __restrict__ va,
    float* __restrict__ scores, float* __restrict__ preds) {
    __shared__ float w_sh[128][31];
    const int b = blockIdx.y, i0 = blockIdx.x * 32;
    const int tid = threadIdx.x;

    float va_r[HID_];
#pragma unroll
    for (int d2 = 0; d2 < HID_; ++d2) va_r[d2] = va[d2];

    for (int i = tid; i < 128 * HID_; i += 256) {
        int r = i / HID_, d2 = i - r * HID_;
        w_sh[r][d2] = W[((size_t)b * S_ + r) * 32 + d2];
    }
    __syncthreads();

    const int il = tid >> 3;
    const int jb = (tid & 7) * 16;
    float u_r[HID_];
    const float* urow = U + ((size_t)b * S_ + i0 + il) * 32;
#pragma unroll
    for (int d2 = 0; d2 < HID_; ++d2) u_r[d2] = urow[d2];

    const size_t obase = ((size_t)b * S_ + (i0 + il)) * S_;
    for (int jj = 0; jj < 16; ++jj) {
        int j = jb + jj;
        float acc = 0.f;
#pragma unroll
        for (int d2 = 0; d2 < HID_; ++d2)
            acc = fmaf(va_r[d2], tanh_acc(u_r[d2] + w_sh[j][d2]), acc);
        scores[obase + j] = acc;
        preds[obase + j] = (sigmoid_acc(acc) >= 0.5f) ? 1.f : 0.f;
    }
}

// ---------------------------------------------------------------------------
// Workspace layout (bytes):
//   Xg   @ 0          : 2*8192*1024*4 = 67,108,864
//   enc  @ 67,108,864 : 64*128*512*4  = 16,777,216
//   U    @ 83,886,080 : 8192*32*4     =  1,048,576
//   W    @ 84,934,656 : 8192*32*4     =  1,048,576
//   Xch  @ 85,983,232 : 128*2*2*128*8 =    524,288
//   sTp  @ 86,507,520 : 4*12*512*8    =    196,608   (total ~86.7 MB)
// ---------------------------------------------------------------------------
extern "C" void kernel_launch(void* const* d_in, const int* in_sizes, int n_in,
                              void* d_out, int out_size, void* d_ws, size_t ws_size,
                              hipStream_t stream) {
    (void)in_sizes; (void)n_in; (void)out_size; (void)ws_size;
    const int* concepts = (const int*)d_in[0];
    const int* lens = (const int*)d_in[1];
    const float* embedding = (const float*)d_in[2];
    const float* Wih_f = (const float*)d_in[3];
    const float* Whh_f = (const float*)d_in[4];
    const float* b_f = (const float*)d_in[5];
    const float* Wih_b = (const float*)d_in[6];
    const float* Whh_b = (const float*)d_in[7];
    const float* b_b = (const float*)d_in[8];
    const float* Ua = (const float*)d_in[9];
    const float* Wa = (const float*)d_in[10];
    const float* va = (const float*)d_in[11];

    char* ws = (char*)d_ws;
    float* Xg = (float*)(ws + 0);
    float* enc = (float*)(ws + 67108864);
    float* U = (float*)(ws + 83886080);
    float* W = (float*)(ws + 84934656);
    unsigned long long* Xch = (unsigned long long*)(ws + 85983232);
    f32x2* sTp = (f32x2*)(ws + 86507520);

    float* scores = (float*)d_out;
    float* preds = scores + (size_t)B_ * S_ * S_;

    // zero handoff slots: packed(tag=0, h=0.0f) == initial state h(0)=0
    hipMemsetAsync(Xch, 0, 524288, stream);

    hipLaunchKernelGGL(prep_sT_kernel, dim3(96), dim3(256), 0, stream,
                       Whh_f, Whh_b, sTp);
    hipLaunchKernelGGL(gemm2_kernel, dim3(512, 2), dim3(256), 0, stream,
                       concepts, embedding, Wih_f, Wih_b, Xg);

    {
        const float* XgA = Xg;
        void* ka[] = {(void*)&XgA, (void*)&Whh_f, (void*)&Whh_b, (void*)&b_f,
                      (void*)&b_b, (void*)&lens, (void*)&enc, (void*)&Xch,
                      (void*)&sTp};
        hipLaunchCooperativeKernel((const void*)lstm_x_kernel, dim3(256),
                                   dim3(512), ka, NL_ * 512 * sizeof(f32x2),
                                   stream);
    }

    hipLaunchKernelGGL(uw_kernel, dim3(4, 64), dim3(256), 0, stream,
                       enc, Ua, Wa, U, W);
    hipLaunchKernelGGL(scores_kernel, dim3(4, 64), dim3(256), 0, stream,
                       U, W, va, scores, preds);
}

// Round 7
// 659.492 us; speedup vs baseline: 3.9554x; 3.9554x over previous
//
#include <hip/hip_runtime.h>

// Problem constants
#define V_  32000
#define E_  256
#define H_  256
#define S_  128
#define B_  64
#define HID_ 30

typedef float f32x2 __attribute__((ext_vector_type(2)));

// Accurate f32 activations (LSTM path — keep libm, proven numerics)
__device__ __forceinline__ float sigmoid_acc(float x) {
    return 1.0f / (1.0f + expf(-x));
}
__device__ __forceinline__ float tanh_acc(float x) {
    return tanhf(x);
}
// Fast tanh for the scores kernel only (v_exp + v_rcp, ~3e-7 abs err)
__device__ __forceinline__ float fast_tanh(float x) {
    return 1.f - 2.f * __builtin_amdgcn_rcpf(1.f + __expf(2.f * x));
}

// ---------------------------------------------------------------------------
// K0: build sT: per (dir, side) the last 12 cols of each Whh row, transposed
// for coalesced per-step streaming. sT[q][r], q = dir*6+side*3+j.
// ---------------------------------------------------------------------------
__global__ __launch_bounds__(256) void prep_stream_kernel(
    const float* __restrict__ Whh_f, const float* __restrict__ Whh_b,
    float4* __restrict__ sT) {
    int i = blockIdx.x * 256 + threadIdx.x;      // < 12*1024
    if (i >= 12 * 1024) return;
    int r = i & 1023;
    int q = i >> 10;                             // 0..11
    int j = q % 3;
    int side = (q % 6) / 3;
    int dir = q / 6;
    const float* Whh = dir ? Whh_b : Whh_f;
    const float* src = Whh + (size_t)r * H_ + side * 128 + 116 + 4 * j;
    sT[(size_t)q * 1024 + r] = make_float4(src[0], src[1], src[2], src[3]);
}

// ---------------------------------------------------------------------------
// K1: f32 input-projection GEMM with fused embedding gather.
// 128x128 tile, 8x8 per thread, KC=32 via LDS. grid (512, 2), block 256.
// ---------------------------------------------------------------------------
#define GKC 32
#define GLD 132

__global__ __launch_bounds__(256, 4) void gemm2_kernel(
    const int* __restrict__ concepts, const float* __restrict__ embedding,
    const float* __restrict__ Wih_f, const float* __restrict__ Wih_b,
    float* __restrict__ Xg) {
    __shared__ float As[GKC][GLD];
    __shared__ float Bs[GKC][GLD];
    const int dir = blockIdx.y;
    const float* Wih = dir ? Wih_b : Wih_f;
    const int mt = blockIdx.x >> 3;
    const int nt = blockIdx.x & 7;
    const int m0 = mt * 128, n0 = nt * 128;
    const int t = threadIdx.x;
    const int tm = (t & 15) * 4;
    const int tn = (t >> 4) * 4;

    int cid[4], rr[4];
#pragma unroll
    for (int i = 0; i < 4; ++i) {
        int flat = t + 256 * i;
        rr[i] = flat >> 3;
        cid[i] = concepts[m0 + rr[i]];
    }

    float acc[8][8];
#pragma unroll
    for (int i = 0; i < 8; ++i)
#pragma unroll
        for (int j = 0; j < 8; ++j) acc[i][j] = 0.f;

    for (int kk = 0; kk < E_; kk += GKC) {
        __syncthreads();
#pragma unroll
        for (int i = 0; i < 4; ++i) {
            int flat = t + 256 * i;
            int r = rr[i];
            int kq = (flat & 7) * 4;
            float4 av = *(const float4*)&embedding[(size_t)cid[i] * E_ + kk + kq];
            float4 bv = *(const float4*)&Wih[(size_t)(n0 + r) * E_ + kk + kq];
            As[kq + 0][r] = av.x; As[kq + 1][r] = av.y;
            As[kq + 2][r] = av.z; As[kq + 3][r] = av.w;
            Bs[kq + 0][r] = bv.x; Bs[kq + 1][r] = bv.y;
            Bs[kq + 2][r] = bv.z; Bs[kq + 3][r] = bv.w;
        }
        __syncthreads();
#pragma unroll
        for (int k = 0; k < GKC; ++k) {
            float4 a0 = *(const float4*)&As[k][tm];
            float4 a1 = *(const float4*)&As[k][tm + 64];
            float4 b0 = *(const float4*)&Bs[k][tn];
            float4 b1 = *(const float4*)&Bs[k][tn + 64];
            float am[8] = {a0.x, a0.y, a0.z, a0.w, a1.x, a1.y, a1.z, a1.w};
            float bn[8] = {b0.x, b0.y, b0.z, b0.w, b1.x, b1.y, b1.z, b1.w};
#pragma unroll
            for (int i = 0; i < 8; ++i)
#pragma unroll
                for (int j = 0; j < 8; ++j)
                    acc[i][j] = fmaf(am[i], bn[j], acc[i][j]);
        }
    }
    float* out = Xg + ((size_t)dir * 8192 + m0) * 1024 + n0;
#pragma unroll
    for (int i = 0; i < 8; ++i) {
        int mr = (i < 4) ? (tm + i) : (tm + 60 + i);
        *(float4*)&out[(size_t)mr * 1024 + tn] =
            make_float4(acc[i][0], acc[i][1], acc[i][2], acc[i][3]);
        *(float4*)&out[(size_t)mr * 1024 + tn + 64] =
            make_float4(acc[i][4], acc[i][5], acc[i][6], acc[i][7]);
    }
}

// ---------------------------------------------------------------------------
// K2: LSTM, K-split pair (round-4 resource layout, v2 exchange protocol).
// 256 WGs x 512 thr (1 WG/CU), both dirs concurrent, cooperative launch.
// w: side = w>>7 (partner = w^128, same XCD under i%8 round-robin),
// P = w&127, dir = P&1, b = P>>1.
// Thread t: rows r0=t, r1=t+512 (both rows of unit u=t&255, gate class
// gc=t>>8: {i,g} or {f,o}), dot over side's 128 cols:
//   40 pair-cols regs + 18 pair-cols LDS + 6 pair-cols streamed (sT).
// Consumers (unit on own side) add x+bias, activate, finalize h locally.
// Producers (unit on partner side) publish both partials to ADJACENT 8B
// slots (packed tag<<32|f32, relaxed agent atomics); consumer dual-spins
// both slots with loads in flight together -> ONE LLC RT per step.
// ---------------------------------------------------------------------------
#define RP_ 40
#define LP_ 18

__global__ __launch_bounds__(512, 2) void lstm_ks2_kernel(
    const float* __restrict__ Xg,     // [2][8192][1024]
    const float* __restrict__ Whh_f, const float* __restrict__ Whh_b,
    const float* __restrict__ b_f, const float* __restrict__ b_b,
    const int* __restrict__ lens,
    float* __restrict__ enc,          // [B][S][512]
    unsigned long long* __restrict__ Xch,  // [P=128][2 par][2 prodside][512]
    const float4* __restrict__ sT) {  // [12][1024]
    extern __shared__ f32x2 Wl[];     // [LP_][1024]
    __shared__ f32x2 h_sh2[64];       // own side's 128 h values
    __shared__ float g_sh[2][128];    // f,o handoff between consumer halves
    const int w = blockIdx.x;
    const int side = w >> 7;
    const int P = w & 127;
    const int dir = P & 1, b = P >> 1;
    const int t = threadIdx.x;
    const int r0 = t, r1 = t + 512;
    const int ul = t & 127;
    const int gc = t >> 8;            // 0: rows {i,g}, 1: rows {f,o}
    const bool mine = (((t >> 7) & 1) == side);  // wave-uniform
    const int base = side << 7;
    const float* Whh = dir ? Whh_b : Whh_f;
    const int len = lens[b];

    // pin weights: rows r0, r1, cols [base, base+80) in regs
    f32x2 w0[RP_], w1[RP_];
    {
        const f32x2* p0 = (const f32x2*)(Whh + (size_t)r0 * H_ + base);
        const f32x2* p1 = (const f32x2*)(Whh + (size_t)r1 * H_ + base);
#pragma unroll
        for (int j = 0; j < RP_; ++j) { w0[j] = p0[j]; w1[j] = p1[j]; }
        // cols [base+80, base+116) in LDS
#pragma unroll
        for (int j = 0; j < LP_; ++j) {
            Wl[j * 1024 + r0] = p0[RP_ + j];
            Wl[j * 1024 + r1] = p1[RP_ + j];
        }
    }
    const float* bias = dir ? b_b : b_f;
    const float bias0 = bias[r0], bias1 = bias[r1];
    const float4* sT0 = sT + (size_t)(dir * 6 + side * 3) * 1024;
    const int pi2 = ((gc << 7) + ul) << 1;   // adjacent slot pair index

    if (t < 64) h_sh2[t] = (f32x2){0.f, 0.f};
    float c = 0.f;                    // cell state (consumers with gc==0)
    __syncthreads();

    // x prefetch (consumers only)
    int srow = dir ? (len - 1) : 0;   // len >= 1 guaranteed
    float x0 = 0.f, x1 = 0.f;
    if (mine) {
        const float* xp = Xg + ((size_t)dir * 8192 + (size_t)srow * B_ + b) * 1024;
        x0 = xp[r0]; x1 = xp[r1];
    }

    for (int s = 0; s < S_; ++s) {
        // streamed weight pairs 58..63 (cols base+116..127), in flight
        float4 s00 = sT0[r0], s01 = sT0[1024 + r0], s02 = sT0[2048 + r0];
        float4 s10 = sT0[r1], s11 = sT0[1024 + r1], s12 = sT0[2048 + r1];
        // next-step x prefetch
        int srow_n = 0;
        float x0n = 0.f, x1n = 0.f;
        if (s + 1 < S_) {
            int ns = s + 1;
            srow_n = dir ? ((ns < len) ? (len - 1 - ns) : ns) : ns;
            if (mine) {
                const float* xp =
                    Xg + ((size_t)dir * 8192 + (size_t)srow_n * B_ + b) * 1024;
                x0n = xp[r0]; x1n = xp[r1];
            }
        }

        // partial dot over own side's 128 cols, rows r0 and r1
        f32x2 a0 = (f32x2){0.f, 0.f}, a1 = (f32x2){0.f, 0.f};
#pragma unroll
        for (int j = 0; j < RP_; ++j) {
            f32x2 hv = h_sh2[j];                  // broadcast
            a0 = __builtin_elementwise_fma(w0[j], hv, a0);
            a1 = __builtin_elementwise_fma(w1[j], hv, a1);
        }
#pragma unroll
        for (int j = 0; j < LP_; ++j) {
            f32x2 hv = h_sh2[RP_ + j];
            f32x2 wa = Wl[j * 1024 + r0];
            f32x2 wb = Wl[j * 1024 + r1];
            a0 = __builtin_elementwise_fma(wa, hv, a0);
            a1 = __builtin_elementwise_fma(wb, hv, a1);
        }
        {
            f32x2 h58 = h_sh2[58], h59 = h_sh2[59], h60 = h_sh2[60];
            f32x2 h61 = h_sh2[61], h62 = h_sh2[62], h63 = h_sh2[63];
            a0 = __builtin_elementwise_fma((f32x2){s00.x, s00.y}, h58, a0);
            a0 = __builtin_elementwise_fma((f32x2){s00.z, s00.w}, h59, a0);
            a0 = __builtin_elementwise_fma((f32x2){s01.x, s01.y}, h60, a0);
            a0 = __builtin_elementwise_fma((f32x2){s01.z, s01.w}, h61, a0);
            a0 = __builtin_elementwise_fma((f32x2){s02.x, s02.y}, h62, a0);
            a0 = __builtin_elementwise_fma((f32x2){s02.z, s02.w}, h63, a0);
            a1 = __builtin_elementwise_fma((f32x2){s10.x, s10.y}, h58, a1);
            a1 = __builtin_elementwise_fma((f32x2){s10.z, s10.w}, h59, a1);
            a1 = __builtin_elementwise_fma((f32x2){s11.x, s11.y}, h60, a1);
            a1 = __builtin_elementwise_fma((f32x2){s11.z, s11.w}, h61, a1);
            a1 = __builtin_elementwise_fma((f32x2){s12.x, s12.y}, h62, a1);
            a1 = __builtin_elementwise_fma((f32x2){s12.z, s12.w}, h63, a1);
        }
        float p0 = a0.x + a0.y, p1 = a1.x + a1.y;

        const unsigned tag = (unsigned)(s + 1);
        float iv = 0.f, gv = 0.f;
        if (!mine) {
            // publish both partials to adjacent slots (one line)
            unsigned long long* sb =
                Xch + (((size_t)P * 2 + (s & 1)) * 2 + side) * 512 + pi2;
            __hip_atomic_store(sb,
                ((unsigned long long)tag << 32) | (unsigned long long)__float_as_uint(p0),
                __ATOMIC_RELAXED, __HIP_MEMORY_SCOPE_AGENT);
            __hip_atomic_store(sb + 1,
                ((unsigned long long)tag << 32) | (unsigned long long)__float_as_uint(p1),
                __ATOMIC_RELAXED, __HIP_MEMORY_SCOPE_AGENT);
        } else {
            // dual-predicated spin: both loads in flight -> one RT
            const unsigned long long* rs =
                Xch + (((size_t)P * 2 + (s & 1)) * 2 + (side ^ 1)) * 512 + pi2;
            unsigned long long q0 = 0, q1 = 0;
            int d0 = 0, d1 = 0;
            for (;;) {
                if (!d0) q0 = __hip_atomic_load(rs, __ATOMIC_RELAXED,
                                                __HIP_MEMORY_SCOPE_AGENT);
                if (!d1) q1 = __hip_atomic_load(rs + 1, __ATOMIC_RELAXED,
                                                __HIP_MEMORY_SCOPE_AGENT);
                d0 = ((unsigned)(q0 >> 32) == tag);
                d1 = ((unsigned)(q1 >> 32) == tag);
                if (d0 & d1) break;
            }
            float g0 = p0 + __uint_as_float((unsigned)q0) + bias0 + x0;
            float g1 = p1 + __uint_as_float((unsigned)q1) + bias1 + x1;
            if (gc == 0) {
                iv = sigmoid_acc(g0);            // i-gate (keep in regs)
                gv = tanh_acc(g1);               // g-gate
            } else {
                g_sh[0][ul] = sigmoid_acc(g0);   // f-gate
                g_sh[1][ul] = sigmoid_acc(g1);   // o-gate
            }
        }
        __syncthreads();   // SYNC1: g_sh ready; h_sh2 fully consumed

        if (mine && gc == 0) {
            float fv = g_sh[0][ul], ov = g_sh[1][ul];
            c = fv * c + iv * gv;
            float h = ov * tanh_acc(c);
            ((float*)h_sh2)[ul] = h;
            int orow = dir ? srow : s;
            enc[((size_t)b * S_ + orow) * 512 + dir * H_ + base + ul] =
                (orow < len) ? h : 0.f;
        }
        __syncthreads();   // SYNC2: h(s+1) ready for next step's dots

        srow = srow_n;
        x0 = x0n; x1 = x1n;
    }
}

// ---------------------------------------------------------------------------
// K3: U = enc@Ua^T, W = enc@Wa^T
// ---------------------------------------------------------------------------
__global__ __launch_bounds__(256) void uw_kernel(
    const float* __restrict__ enc, const float* __restrict__ Ua,
    const float* __restrict__ Wa, float* __restrict__ U, float* __restrict__ Wout) {
    __shared__ float wgt[60][129];
    __shared__ float erow[4][128];
    const int tid = threadIdx.x;
    const int b = blockIdx.y, s0 = blockIdx.x * 32;
    const int rl = tid >> 6;
    const int d = tid & 63;
    const int dd = d & 31;
    const int isW = d >> 5;
    float acc[8];
#pragma unroll
    for (int i = 0; i < 8; ++i) acc[i] = 0.f;

    for (int kk = 0; kk < 4; ++kk) {
        __syncthreads();
        for (int i = tid; i < 30 * 128; i += 256) {
            int r = i >> 7, k = i & 127;
            wgt[r][k] = Ua[(size_t)r * 512 + kk * 128 + k];
            wgt[r + 30][k] = Wa[(size_t)r * 512 + kk * 128 + k];
        }
        for (int chunk = 0; chunk < 8; ++chunk) {
            __syncthreads();
            for (int i = tid; i < 4 * 128; i += 256) {
                int r = i >> 7, k = i & 127;
                erow[r][k] = enc[((size_t)b * S_ + (s0 + chunk * 4 + r)) * 512 + kk * 128 + k];
            }
            __syncthreads();
            if (dd < HID_) {
                const float* wr = wgt[dd + 30 * isW];
                const float* er = erow[rl];
                float a = acc[chunk];
#pragma unroll
                for (int k = 0; k < 128; ++k) a = fmaf(er[k], wr[k], a);
                acc[chunk] = a;
            }
        }
    }
    if (dd < HID_) {
        float* dst = isW ? Wout : U;
#pragma unroll
        for (int chunk = 0; chunk < 8; ++chunk)
            dst[((size_t)b * S_ + (s0 + chunk * 4 + rl)) * 32 + dd] = acc[chunk];
    }
}

// ---------------------------------------------------------------------------
// K4: scores + predictions (fast tanh; sigmoid boundary via expf)
// ---------------------------------------------------------------------------
__global__ __launch_bounds__(256) void scores_kernel(
    const float* __restrict__ U, const float* __restrict__ W,
    const float* __restrict__ va,
    float* __restrict__ scores, float* __restrict__ preds) {
    __shared__ float w_sh[128][31];
    const int b = blockIdx.y, i0 = blockIdx.x * 32;
    const int tid = threadIdx.x;

    float va_r[HID_];
#pragma unroll
    for (int d2 = 0; d2 < HID_; ++d2) va_r[d2] = va[d2];

    for (int i = tid; i < 128 * HID_; i += 256) {
        int r = i / HID_, d2 = i - r * HID_;
        w_sh[r][d2] = W[((size_t)b * S_ + r) * 32 + d2];
    }
    __syncthreads();

    const int il = tid >> 3;
    const int jb = (tid & 7) * 16;
    float u_r[HID_];
    const float* urow = U + ((size_t)b * S_ + i0 + il) * 32;
#pragma unroll
    for (int d2 = 0; d2 < HID_; ++d2) u_r[d2] = urow[d2];

    const size_t obase = ((size_t)b * S_ + (i0 + il)) * S_;
    for (int jj = 0; jj < 16; ++jj) {
        int j = jb + jj;
        float acc = 0.f;
#pragma unroll
        for (int d2 = 0; d2 < HID_; ++d2)
            acc = fmaf(va_r[d2], fast_tanh(u_r[d2] + w_sh[j][d2]), acc);
        scores[obase + j] = acc;
        preds[obase + j] = (sigmoid_acc(acc) >= 0.5f) ? 1.f : 0.f;
    }
}

// ---------------------------------------------------------------------------
// Workspace layout (bytes):
//   Xg   @ 0          : 2*8192*1024*4 = 67,108,864
//   enc  @ 67,108,864 : 64*128*512*4  = 16,777,216
//   U    @ 83,886,080 : 8192*32*4     =  1,048,576
//   W    @ 84,934,656 : 8192*32*4     =  1,048,576
//   Xch  @ 85,983,232 : 128*2*2*512*8 =  2,097,152
//   sT   @ 88,080,384 : 12*1024*16    =    196,608   (total ~88.3 MB)
// ---------------------------------------------------------------------------
extern "C" void kernel_launch(void* const* d_in, const int* in_sizes, int n_in,
                              void* d_out, int out_size, void* d_ws, size_t ws_size,
                              hipStream_t stream) {
    (void)in_sizes; (void)n_in; (void)out_size; (void)ws_size;
    const int* concepts = (const int*)d_in[0];
    const int* lens = (const int*)d_in[1];
    const float* embedding = (const float*)d_in[2];
    const float* Wih_f = (const float*)d_in[3];
    const float* Whh_f = (const float*)d_in[4];
    const float* b_f = (const float*)d_in[5];
    const float* Wih_b = (const float*)d_in[6];
    const float* Whh_b = (const float*)d_in[7];
    const float* b_b = (const float*)d_in[8];
    const float* Ua = (const float*)d_in[9];
    const float* Wa = (const float*)d_in[10];
    const float* va = (const float*)d_in[11];

    char* ws = (char*)d_ws;
    float* Xg = (float*)(ws + 0);
    float* enc = (float*)(ws + 67108864);
    float* U = (float*)(ws + 83886080);
    float* W = (float*)(ws + 84934656);
    unsigned long long* Xch = (unsigned long long*)(ws + 85983232);
    float4* sT = (float4*)(ws + 88080384);

    float* scores = (float*)d_out;
    float* preds = scores + (size_t)B_ * S_ * S_;

    // zero handoff slots (tag 0 != any expected tag >= 1)
    hipMemsetAsync(Xch, 0, 2097152, stream);

    hipLaunchKernelGGL(prep_stream_kernel, dim3(48), dim3(256), 0, stream,
                       Whh_f, Whh_b, sT);
    hipLaunchKernelGGL(gemm2_kernel, dim3(512, 2), dim3(256), 0, stream,
                       concepts, embedding, Wih_f, Wih_b, Xg);

    {
        const float* XgA = Xg;
        void* ka[] = {(void*)&XgA, (void*)&Whh_f, (void*)&Whh_b, (void*)&b_f,
                      (void*)&b_b, (void*)&lens, (void*)&enc, (void*)&Xch,
                      (void*)&sT};
        hipLaunchCooperativeKernel((const void*)lstm_ks2_kernel, dim3(256),
                                   dim3(512), ka, LP_ * 1024 * sizeof(f32x2),
                                   stream);
    }

    hipLaunchKernelGGL(uw_kernel, dim3(4, 64), dim3(256), 0, stream,
                       enc, Ua, Wa, U, W);
    hipLaunchKernelGGL(scores_kernel, dim3(4, 64), dim3(256), 0, stream,
                       U, W, va, scores, preds);
}

// Round 10
// 598.587 us; speedup vs baseline: 4.3578x; 1.1017x over previous
//
#include <hip/hip_runtime.h>

// Problem constants
#define V_  32000
#define E_  256
#define H_  256
#define S_  128
#define B_  64
#define HID_ 30

typedef float f32x2 __attribute__((ext_vector_type(2)));

// Accurate f32 activations (LSTM path)
__device__ __forceinline__ float sigmoid_acc(float x) {
    return 1.0f / (1.0f + expf(-x));
}
__device__ __forceinline__ float tanh_acc(float x) {
    return tanhf(x);
}
// Fast tanh for the scores kernel only (~3e-7 abs err)
__device__ __forceinline__ float fast_tanh(float x) {
    return 1.f - 2.f * __builtin_amdgcn_rcpf(1.f + __expf(2.f * x));
}

// Fast-path exchange ops (64-bit scalar operands -> VGPR pairs).
// NOTE gfx950 assembler syntax: offset: immediate must precede cache flags
// ("off offset:8 sc0"; "off sc0 offset:8" does NOT assemble).
// Producer: two plain dwordx2 stores (write-through L1 -> home XCD L2).
// Consumer: two sc0 loads (L1 bypass, reads shared XCD L2), one waitcnt.
__device__ __forceinline__ void store_l2x2(unsigned long long* p,
                                           unsigned long long a,
                                           unsigned long long b) {
    asm volatile("global_store_dwordx2 %2, %0, off\n\t"
                 "global_store_dwordx2 %2, %1, off offset:8"
                 :: "v"(a), "v"(b), "v"(p) : "memory");
}
__device__ __forceinline__ void load_l2x2(const unsigned long long* p,
                                          unsigned long long& a,
                                          unsigned long long& b) {
    asm volatile("global_load_dwordx2 %0, %2, off sc0\n\t"
                 "global_load_dwordx2 %1, %2, off offset:8 sc0\n\t"
                 "s_waitcnt vmcnt(0)"
                 : "=&v"(a), "=&v"(b) : "v"(p) : "memory");
}

// ---------------------------------------------------------------------------
// K0: build sT: per (dir, side) the last 12 cols of each Whh row, transposed
// for coalesced per-step streaming. sT[q][r], q = dir*6+side*3+j.
// ---------------------------------------------------------------------------
__global__ __launch_bounds__(256) void prep_stream_kernel(
    const float* __restrict__ Whh_f, const float* __restrict__ Whh_b,
    float4* __restrict__ sT) {
    int i = blockIdx.x * 256 + threadIdx.x;      // < 12*1024
    if (i >= 12 * 1024) return;
    int r = i & 1023;
    int q = i >> 10;                             // 0..11
    int j = q % 3;
    int side = (q % 6) / 3;
    int dir = q / 6;
    const float* Whh = dir ? Whh_b : Whh_f;
    const float* src = Whh + (size_t)r * H_ + side * 128 + 116 + 4 * j;
    sT[(size_t)q * 1024 + r] = make_float4(src[0], src[1], src[2], src[3]);
}

// ---------------------------------------------------------------------------
// K1: f32 input-projection GEMM with fused embedding gather.
// 128x128 tile, 8x8 per thread, KC=32 via LDS. grid (512, 2), block 256.
// ---------------------------------------------------------------------------
#define GKC 32
#define GLD 132

__global__ __launch_bounds__(256, 4) void gemm2_kernel(
    const int* __restrict__ concepts, const float* __restrict__ embedding,
    const float* __restrict__ Wih_f, const float* __restrict__ Wih_b,
    float* __restrict__ Xg) {
    __shared__ float As[GKC][GLD];
    __shared__ float Bs[GKC][GLD];
    const int dir = blockIdx.y;
    const float* Wih = dir ? Wih_b : Wih_f;
    const int mt = blockIdx.x >> 3;
    const int nt = blockIdx.x & 7;
    const int m0 = mt * 128, n0 = nt * 128;
    const int t = threadIdx.x;
    const int tm = (t & 15) * 4;
    const int tn = (t >> 4) * 4;

    int cid[4], rr[4];
#pragma unroll
    for (int i = 0; i < 4; ++i) {
        int flat = t + 256 * i;
        rr[i] = flat >> 3;
        cid[i] = concepts[m0 + rr[i]];
    }

    float acc[8][8];
#pragma unroll
    for (int i = 0; i < 8; ++i)
#pragma unroll
        for (int j = 0; j < 8; ++j) acc[i][j] = 0.f;

    for (int kk = 0; kk < E_; kk += GKC) {
        __syncthreads();
#pragma unroll
        for (int i = 0; i < 4; ++i) {
            int flat = t + 256 * i;
            int r = rr[i];
            int kq = (flat & 7) * 4;
            float4 av = *(const float4*)&embedding[(size_t)cid[i] * E_ + kk + kq];
            float4 bv = *(const float4*)&Wih[(size_t)(n0 + r) * E_ + kk + kq];
            As[kq + 0][r] = av.x; As[kq + 1][r] = av.y;
            As[kq + 2][r] = av.z; As[kq + 3][r] = av.w;
            Bs[kq + 0][r] = bv.x; Bs[kq + 1][r] = bv.y;
            Bs[kq + 2][r] = bv.z; Bs[kq + 3][r] = bv.w;
        }
        __syncthreads();
#pragma unroll
        for (int k = 0; k < GKC; ++k) {
            float4 a0 = *(const float4*)&As[k][tm];
            float4 a1 = *(const float4*)&As[k][tm + 64];
            float4 b0 = *(const float4*)&Bs[k][tn];
            float4 b1 = *(const float4*)&Bs[k][tn + 64];
            float am[8] = {a0.x, a0.y, a0.z, a0.w, a1.x, a1.y, a1.z, a1.w};
            float bn[8] = {b0.x, b0.y, b0.z, b0.w, b1.x, b1.y, b1.z, b1.w};
#pragma unroll
            for (int i = 0; i < 8; ++i)
#pragma unroll
                for (int j = 0; j < 8; ++j)
                    acc[i][j] = fmaf(am[i], bn[j], acc[i][j]);
        }
    }
    float* out = Xg + ((size_t)dir * 8192 + m0) * 1024 + n0;
#pragma unroll
    for (int i = 0; i < 8; ++i) {
        int mr = (i < 4) ? (tm + i) : (tm + 60 + i);
        *(float4*)&out[(size_t)mr * 1024 + tn] =
            make_float4(acc[i][0], acc[i][1], acc[i][2], acc[i][3]);
        *(float4*)&out[(size_t)mr * 1024 + tn + 64] =
            make_float4(acc[i][4], acc[i][5], acc[i][6], acc[i][7]);
    }
}

// ---------------------------------------------------------------------------
// K2: LSTM, K-split pair with dual-path (L2-fast + LLC-safe) exchange.
// 256 WGs x 512 thr (1 WG/CU), both dirs concurrent, cooperative launch.
// w: side = w>>7 (partner = w^128: same XCD under i%8 round-robin),
// P = w&127, dir = P&1, b = P>>1.
// Thread t: rows r0=t, r1=t+512, dot over side's 128 cols:
//   39 pair-cols regs + 19 pair-cols LDS + 6 pair-cols streamed (sT).
// Producers publish {tag|p0},{tag|p1} as two plain dwordx2 (fast, XCD L2)
// AND packed 64-bit agent atomics (slow, LLC). Consumers poll both paths,
// tag-validated -> correct under any WG->XCD placement.
// ---------------------------------------------------------------------------
#define RP_ 39
#define LP_ 19

__global__ __launch_bounds__(512, 2) void lstm_ks3_kernel(
    const float* __restrict__ Xg,     // [2][8192][1024]
    const float* __restrict__ Whh_f, const float* __restrict__ Whh_b,
    const float* __restrict__ b_f, const float* __restrict__ b_b,
    const int* __restrict__ lens,
    float* __restrict__ enc,          // [B][S][512]
    unsigned long long* __restrict__ Fch,  // [P=128][2 par][2 prodside][512]
    unsigned long long* __restrict__ Sch,  // [P=128][2 par][2 prodside][512]
    const float4* __restrict__ sT) {  // [12][1024]
    extern __shared__ f32x2 Wl[];     // [LP_][1024]
    __shared__ f32x2 h_sh2[64];       // own side's 128 h values
    __shared__ float g_sh[2][128];    // f,o handoff between consumer halves
    const int w = blockIdx.x;
    const int side = w >> 7;
    const int P = w & 127;
    const int dir = P & 1, b = P >> 1;
    const int t = threadIdx.x;
    const int r0 = t, r1 = t + 512;
    const int ul = t & 127;
    const int gc = t >> 8;            // 0: rows {i,g}, 1: rows {f,o}
    const bool mine = (((t >> 7) & 1) == side);  // wave-uniform
    const int base = side << 7;
    const int idx = (gc << 7) + ul;   // slot index 0..255
    const float* Whh = dir ? Whh_b : Whh_f;
    const int len = lens[b];

    // pin weights: rows r0, r1, cols [base, base+78) in regs
    f32x2 w0[RP_], w1[RP_];
    {
        const f32x2* p0 = (const f32x2*)(Whh + (size_t)r0 * H_ + base);
        const f32x2* p1 = (const f32x2*)(Whh + (size_t)r1 * H_ + base);
#pragma unroll
        for (int j = 0; j < RP_; ++j) { w0[j] = p0[j]; w1[j] = p1[j]; }
        // cols [base+78, base+116) in LDS
#pragma unroll
        for (int j = 0; j < LP_; ++j) {
            Wl[j * 1024 + r0] = p0[RP_ + j];
            Wl[j * 1024 + r1] = p1[RP_ + j];
        }
    }
    const float* bias = dir ? b_b : b_f;
    const float bias0 = bias[r0], bias1 = bias[r1];
    const float4* sT0 = sT + (size_t)(dir * 6 + side * 3) * 1024;

    // exchange pointers (per-parity precomputed)
    unsigned long long* fw0 = Fch + (((size_t)P * 2 + 0) * 2 + side) * 512 + 2 * idx;
    unsigned long long* fw1 = Fch + (((size_t)P * 2 + 1) * 2 + side) * 512 + 2 * idx;
    const unsigned long long* fr0 =
        Fch + (((size_t)P * 2 + 0) * 2 + (side ^ 1)) * 512 + 2 * idx;
    const unsigned long long* fr1 =
        Fch + (((size_t)P * 2 + 1) * 2 + (side ^ 1)) * 512 + 2 * idx;
    unsigned long long* sw0 = Sch + (((size_t)P * 2 + 0) * 2 + side) * 512 + 2 * idx;
    unsigned long long* sw1 = Sch + (((size_t)P * 2 + 1) * 2 + side) * 512 + 2 * idx;
    const unsigned long long* sr0 =
        Sch + (((size_t)P * 2 + 0) * 2 + (side ^ 1)) * 512 + 2 * idx;
    const unsigned long long* sr1 =
        Sch + (((size_t)P * 2 + 1) * 2 + (side ^ 1)) * 512 + 2 * idx;

    if (t < 64) h_sh2[t] = (f32x2){0.f, 0.f};
    float c = 0.f;                    // cell state (consumers with gc==0)
    __syncthreads();

    // x prefetch (consumers only)
    int srow = dir ? (len - 1) : 0;   // len >= 1 guaranteed
    float x0 = 0.f, x1 = 0.f;
    if (mine) {
        const float* xp = Xg + ((size_t)dir * 8192 + (size_t)srow * B_ + b) * 1024;
        x0 = xp[r0]; x1 = xp[r1];
    }

    for (int s = 0; s < S_; ++s) {
        // streamed weight pairs 58..63 (cols base+116..127), in flight
        float4 s00 = sT0[r0], s01 = sT0[1024 + r0], s02 = sT0[2048 + r0];
        float4 s10 = sT0[r1], s11 = sT0[1024 + r1], s12 = sT0[2048 + r1];
        // next-step x prefetch
        int srow_n = 0;
        float x0n = 0.f, x1n = 0.f;
        if (s + 1 < S_) {
            int ns = s + 1;
            srow_n = dir ? ((ns < len) ? (len - 1 - ns) : ns) : ns;
            if (mine) {
                const float* xp =
                    Xg + ((size_t)dir * 8192 + (size_t)srow_n * B_ + b) * 1024;
                x0n = xp[r0]; x1n = xp[r1];
            }
        }

        // partial dot over own side's 128 cols, rows r0 and r1
        f32x2 a0 = (f32x2){0.f, 0.f}, a1 = (f32x2){0.f, 0.f};
#pragma unroll
        for (int j = 0; j < RP_; ++j) {
            f32x2 hv = h_sh2[j];                  // broadcast
            a0 = __builtin_elementwise_fma(w0[j], hv, a0);
            a1 = __builtin_elementwise_fma(w1[j], hv, a1);
        }
#pragma unroll
        for (int j = 0; j < LP_; ++j) {
            f32x2 hv = h_sh2[RP_ + j];
            f32x2 wa = Wl[j * 1024 + r0];
            f32x2 wb = Wl[j * 1024 + r1];
            a0 = __builtin_elementwise_fma(wa, hv, a0);
            a1 = __builtin_elementwise_fma(wb, hv, a1);
        }
        {
            f32x2 h58 = h_sh2[58], h59 = h_sh2[59], h60 = h_sh2[60];
            f32x2 h61 = h_sh2[61], h62 = h_sh2[62], h63 = h_sh2[63];
            a0 = __builtin_elementwise_fma((f32x2){s00.x, s00.y}, h58, a0);
            a0 = __builtin_elementwise_fma((f32x2){s00.z, s00.w}, h59, a0);
            a0 = __builtin_elementwise_fma((f32x2){s01.x, s01.y}, h60, a0);
            a0 = __builtin_elementwise_fma((f32x2){s01.z, s01.w}, h61, a0);
            a0 = __builtin_elementwise_fma((f32x2){s02.x, s02.y}, h62, a0);
            a0 = __builtin_elementwise_fma((f32x2){s02.z, s02.w}, h63, a0);
            a1 = __builtin_elementwise_fma((f32x2){s10.x, s10.y}, h58, a1);
            a1 = __builtin_elementwise_fma((f32x2){s10.z, s10.w}, h59, a1);
            a1 = __builtin_elementwise_fma((f32x2){s11.x, s11.y}, h60, a1);
            a1 = __builtin_elementwise_fma((f32x2){s11.z, s11.w}, h61, a1);
            a1 = __builtin_elementwise_fma((f32x2){s12.x, s12.y}, h62, a1);
            a1 = __builtin_elementwise_fma((f32x2){s12.z, s12.w}, h63, a1);
        }
        float p0 = a0.x + a0.y, p1 = a1.x + a1.y;

        const unsigned tag = (unsigned)(s + 1);
        float iv = 0.f, gv = 0.f;
        if (!mine) {
            unsigned long long k0 =
                ((unsigned long long)tag << 32) | (unsigned long long)__float_as_uint(p0);
            unsigned long long k1 =
                ((unsigned long long)tag << 32) | (unsigned long long)__float_as_uint(p1);
            // fast path: two plain 8B stores, same 16B line (XCD L2)
            store_l2x2((s & 1) ? fw1 : fw0, k0, k1);
            // slow path: LLC-coherent packed atomics (placement-safe)
            unsigned long long* sb = (s & 1) ? sw1 : sw0;
            __hip_atomic_store(sb, k0, __ATOMIC_RELAXED, __HIP_MEMORY_SCOPE_AGENT);
            __hip_atomic_store(sb + 1, k1, __ATOMIC_RELAXED, __HIP_MEMORY_SCOPE_AGENT);
        } else {
            const unsigned long long* fr = (s & 1) ? fr1 : fr0;
            const unsigned long long* sr = (s & 1) ? sr1 : sr0;
            float q0f, q1f;
            for (;;) {
                unsigned long long f0, f1;
                load_l2x2(fr, f0, f1);
                if ((unsigned)(f0 >> 32) == tag && (unsigned)(f1 >> 32) == tag) {
                    q0f = __uint_as_float((unsigned)f0);
                    q1f = __uint_as_float((unsigned)f1);
                    break;
                }
                unsigned long long a0q = __hip_atomic_load(
                    sr, __ATOMIC_RELAXED, __HIP_MEMORY_SCOPE_AGENT);
                unsigned long long a1q = __hip_atomic_load(
                    sr + 1, __ATOMIC_RELAXED, __HIP_MEMORY_SCOPE_AGENT);
                if ((unsigned)(a0q >> 32) == tag && (unsigned)(a1q >> 32) == tag) {
                    q0f = __uint_as_float((unsigned)a0q);
                    q1f = __uint_as_float((unsigned)a1q);
                    break;
                }
            }
            float g0 = p0 + q0f + bias0 + x0;
            float g1 = p1 + q1f + bias1 + x1;
            if (gc == 0) {
                iv = sigmoid_acc(g0);            // i-gate (keep in regs)
                gv = tanh_acc(g1);               // g-gate
            } else {
                g_sh[0][ul] = sigmoid_acc(g0);   // f-gate
                g_sh[1][ul] = sigmoid_acc(g1);   // o-gate
            }
        }
        __syncthreads();   // SYNC1: g_sh ready; h_sh2 fully consumed

        if (mine && gc == 0) {
            float fv = g_sh[0][ul], ov = g_sh[1][ul];
            c = fv * c + iv * gv;
            float h = ov * tanh_acc(c);
            ((float*)h_sh2)[ul] = h;
            int orow = dir ? srow : s;
            enc[((size_t)b * S_ + orow) * 512 + dir * H_ + base + ul] =
                (orow < len) ? h : 0.f;
        }
        __syncthreads();   // SYNC2: h(s+1) ready for next step's dots

        srow = srow_n;
        x0 = x0n; x1 = x1n;
    }
}

// ---------------------------------------------------------------------------
// K3: U = enc@Ua^T, W = enc@Wa^T
// ---------------------------------------------------------------------------
__global__ __launch_bounds__(256) void uw_kernel(
    const float* __restrict__ enc, const float* __restrict__ Ua,
    const float* __restrict__ Wa, float* __restrict__ U, float* __restrict__ Wout) {
    __shared__ float wgt[60][129];
    __shared__ float erow[4][128];
    const int tid = threadIdx.x;
    const int b = blockIdx.y, s0 = blockIdx.x * 32;
    const int rl = tid >> 6;
    const int d = tid & 63;
    const int dd = d & 31;
    const int isW = d >> 5;
    float acc[8];
#pragma unroll
    for (int i = 0; i < 8; ++i) acc[i] = 0.f;

    for (int kk = 0; kk < 4; ++kk) {
        __syncthreads();
        for (int i = tid; i < 30 * 128; i += 256) {
            int r = i >> 7, k = i & 127;
            wgt[r][k] = Ua[(size_t)r * 512 + kk * 128 + k];
            wgt[r + 30][k] = Wa[(size_t)r * 512 + kk * 128 + k];
        }
        for (int chunk = 0; chunk < 8; ++chunk) {
            __syncthreads();
            for (int i = tid; i < 4 * 128; i += 256) {
                int r = i >> 7, k = i & 127;
                erow[r][k] = enc[((size_t)b * S_ + (s0 + chunk * 4 + r)) * 512 + kk * 128 + k];
            }
            __syncthreads();
            if (dd < HID_) {
                const float* wr = wgt[dd + 30 * isW];
                const float* er = erow[rl];
                float a = acc[chunk];
#pragma unroll
                for (int k = 0; k < 128; ++k) a = fmaf(er[k], wr[k], a);
                acc[chunk] = a;
            }
        }
    }
    if (dd < HID_) {
        float* dst = isW ? Wout : U;
#pragma unroll
        for (int chunk = 0; chunk < 8; ++chunk)
            dst[((size_t)b * S_ + (s0 + chunk * 4 + rl)) * 32 + dd] = acc[chunk];
    }
}

// ---------------------------------------------------------------------------
// K4: scores + predictions
// ---------------------------------------------------------------------------
__global__ __launch_bounds__(256) void scores_kernel(
    const float* __restrict__ U, const float* __restrict__ W,
    const float* __restrict__ va,
    float* __restrict__ scores, float* __restrict__ preds) {
    __shared__ float w_sh[128][31];
    const int b = blockIdx.y, i0 = blockIdx.x * 32;
    const int tid = threadIdx.x;

    float va_r[HID_];
#pragma unroll
    for (int d2 = 0; d2 < HID_; ++d2) va_r[d2] = va[d2];

    for (int i = tid; i < 128 * HID_; i += 256) {
        int r = i / HID_, d2 = i - r * HID_;
        w_sh[r][d2] = W[((size_t)b * S_ + r) * 32 + d2];
    }
    __syncthreads();

    const int il = tid >> 3;
    const int jb = (tid & 7) * 16;
    float u_r[HID_];
    const float* urow = U + ((size_t)b * S_ + i0 + il) * 32;
#pragma unroll
    for (int d2 = 0; d2 < HID_; ++d2) u_r[d2] = urow[d2];

    const size_t obase = ((size_t)b * S_ + (i0 + il)) * S_;
    for (int jj = 0; jj < 16; ++jj) {
        int j = jb + jj;
        float acc = 0.f;
#pragma unroll
        for (int d2 = 0; d2 < HID_; ++d2)
            acc = fmaf(va_r[d2], fast_tanh(u_r[d2] + w_sh[j][d2]), acc);
        scores[obase + j] = acc;
        preds[obase + j] = (sigmoid_acc(acc) >= 0.5f) ? 1.f : 0.f;
    }
}

// ---------------------------------------------------------------------------
// Workspace layout (bytes):
//   Xg   @ 0          : 2*8192*1024*4 = 67,108,864
//   enc  @ 67,108,864 : 64*128*512*4  = 16,777,216
//   U    @ 83,886,080 : 8192*32*4     =  1,048,576
//   W    @ 84,934,656 : 8192*32*4     =  1,048,576
//   Fch  @ 85,983,232 : 128*2*2*512*8 =  2,097,152
//   Sch  @ 88,080,384 : 128*2*2*512*8 =  2,097,152
//   sT   @ 90,177,536 : 12*1024*16    =    196,608   (total ~90.4 MB)
// ---------------------------------------------------------------------------
extern "C" void kernel_launch(void* const* d_in, const int* in_sizes, int n_in,
                              void* d_out, int out_size, void* d_ws, size_t ws_size,
                              hipStream_t stream) {
    (void)in_sizes; (void)n_in; (void)out_size; (void)ws_size;
    const int* concepts = (const int*)d_in[0];
    const int* lens = (const int*)d_in[1];
    const float* embedding = (const float*)d_in[2];
    const float* Wih_f = (const float*)d_in[3];
    const float* Whh_f = (const float*)d_in[4];
    const float* b_f = (const float*)d_in[5];
    const float* Wih_b = (const float*)d_in[6];
    const float* Whh_b = (const float*)d_in[7];
    const float* b_b = (const float*)d_in[8];
    const float* Ua = (const float*)d_in[9];
    const float* Wa = (const float*)d_in[10];
    const float* va = (const float*)d_in[11];

    char* ws = (char*)d_ws;
    float* Xg = (float*)(ws + 0);
    float* enc = (float*)(ws + 67108864);
    float* U = (float*)(ws + 83886080);
    float* W = (float*)(ws + 84934656);
    unsigned long long* Fch = (unsigned long long*)(ws + 85983232);
    unsigned long long* Sch = (unsigned long long*)(ws + 88080384);
    float4* sT = (float4*)(ws + 90177536);

    float* scores = (float*)d_out;
    float* preds = scores + (size_t)B_ * S_ * S_;

    // zero handoff slots (tag 0 != any expected tag >= 1); Fch+Sch contiguous
    (void)hipMemsetAsync(Fch, 0, 2 * 2097152, stream);

    hipLaunchKernelGGL(prep_stream_kernel, dim3(48), dim3(256), 0, stream,
                       Whh_f, Whh_b, sT);
    hipLaunchKernelGGL(gemm2_kernel, dim3(512, 2), dim3(256), 0, stream,
                       concepts, embedding, Wih_f, Wih_b, Xg);

    {
        const float* XgA = Xg;
        void* ka[] = {(void*)&XgA, (void*)&Whh_f, (void*)&Whh_b, (void*)&b_f,
                      (void*)&b_b, (void*)&lens, (void*)&enc, (void*)&Fch,
                      (void*)&Sch, (void*)&sT};
        (void)hipLaunchCooperativeKernel((const void*)lstm_ks3_kernel, dim3(256),
                                         dim3(512), ka, LP_ * 1024 * sizeof(f32x2),
                                         stream);
    }

    hipLaunchKernelGGL(uw_kernel, dim3(4, 64), dim3(256), 0, stream,
                       enc, Ua, Wa, U, W);
    hipLaunchKernelGGL(scores_kernel, dim3(4, 64), dim3(256), 0, stream,
                       U, W, va, scores, preds);
}